// Round 9
// baseline (308.352 us; speedup 1.0000x reference)
//
#include <hip/hip_runtime.h>

// ---------------------------------------------------------------------------
// SelectiveRelOnlyEncodeDecodeMLP: 1M edges -> rel_pose(16) -> MLP 16-128-128-128-16
// Fused persistent kernel. Matmuls run on f16 matrix cores with a 2-plane
// hi/lo split (lo plane scaled by 2^11, accumulated separately, combined as
// acc0 + accL*2^-11) -> per-product residual ~2^-21 (fp32-grade vs 2.3e-2
// threshold). Weights pre-fragmented into MFMA lane order and pinned in VGPRs;
// activations ping-pong in LDS; bias folded into MFMA C-init.
// ---------------------------------------------------------------------------

typedef _Float16       f16x8  __attribute__((ext_vector_type(8)));
typedef __fp16         h16x2  __attribute__((ext_vector_type(2)));  // cvt_pkrtz native
typedef unsigned short u16x8  __attribute__((ext_vector_type(8)));
typedef float          f32x16 __attribute__((ext_vector_type(16)));
typedef float          f32x4  __attribute__((ext_vector_type(4)));
typedef unsigned int   u32x2  __attribute__((ext_vector_type(2)));
typedef unsigned int   u32x4  __attribute__((ext_vector_type(4)));

#define N_EDGES_C 1000000
#define NTILES    15625      // 64 edges per tile
#define GRID_MAIN 512        // 2 blocks/CU * 256 CU
#define INV2K     4.8828125e-4f   // 2^-11

__device__ __forceinline__ f32x16 mfma32(f16x8 a, f16x8 b, f32x16 c) {
  return __builtin_amdgcn_mfma_f32_32x32x16_f16(a, b, c, 0, 0, 0);
}
__device__ __forceinline__ f32x4 mfma16(f16x8 a, f16x8 b, f32x4 c) {
  return __builtin_amdgcn_mfma_f32_16x16x32_f16(a, b, c, 0, 0, 0);
}

// split two floats into packed f16 hi pair + packed scaled-lo pair.
// v = hi + lo*2^-11 + eps, |eps| <~ 2^-21 |v|.  (v - (f32)hi is Sterbenz-exact,
// *2048 is exact; cvt_pkrtz rounds toward zero: <=1 ulp.)
__device__ __forceinline__ void split_pair_f16(float v0, float v1,
                                               unsigned int& h, unsigned int& lo) {
  h16x2 hp = __builtin_amdgcn_cvt_pkrtz(v0, v1);
  float r0 = (v0 - (float)hp[0]) * 2048.0f;
  float r1 = (v1 - (float)hp[1]) * 2048.0f;
  h16x2 lp = __builtin_amdgcn_cvt_pkrtz(r0, r1);
  h  = __builtin_bit_cast(unsigned int, hp);
  lo = __builtin_bit_cast(unsigned int, lp);
}

__device__ __forceinline__ void q2m(float w, float x, float y, float z, float* r) {
  r[0] = 1.f - 2.f*(y*y + z*z); r[1] = 2.f*(x*y - z*w);       r[2] = 2.f*(x*z + y*w);
  r[3] = 2.f*(x*y + z*w);       r[4] = 1.f - 2.f*(x*x + z*z); r[5] = 2.f*(y*z - x*w);
  r[6] = 2.f*(x*z - y*w);       r[7] = 2.f*(y*z + x*w);       r[8] = 1.f - 2.f*(x*x + y*y);
}

// ---------------------------------------------------------------------------
// Prep: split weights into f16 hi + f16 lo*2^11 planes, packed in MFMA
// fragment lane order (64 lanes x 16B per fragment).
//   32x32x16:  lane l holds A[row=l&31][k=(l>>5)*8 + j],  A = W^T
//   16x16x32:  lane l holds A[row=l&15][k=(l>>4)*8 + j],  A = W4^T
// (k relabeling is contraction-invariant: A and B fragments use the same
//  per-lane k map, so only the C/D layout must match HW.)
// Frag ids: 0..7 W1[Mt(4)][p(2)] | 8..71 W2[Mt(4)][kt(8)][p(2)]
//           72..135 W3 same      | 136..143 W4[kt(4)][p(2)]
// ---------------------------------------------------------------------------
__global__ void prep_frags(const float* __restrict__ w1, const float* __restrict__ w2,
                           const float* __restrict__ w3, const float* __restrict__ w4,
                           unsigned short* __restrict__ F) {
  int t = blockIdx.x * blockDim.x + threadIdx.x;
  if (t >= 144 * 64) return;
  int f = t >> 6, l = t & 63;
  const float* W; int ldW; int Mt = 0, kt = 0, p = 0; bool is16 = false;
  if (f < 8)        { W = w1; ldW = 128; Mt = f >> 1;       p = f & 1;  kt = 0; }
  else if (f < 72)  { int g = f - 8;   W = w2; ldW = 128; p = g & 1; kt = (g >> 1) & 7; Mt = g >> 4; }
  else if (f < 136) { int g = f - 72;  W = w3; ldW = 128; p = g & 1; kt = (g >> 1) & 7; Mt = g >> 4; }
  else              { int g = f - 136; W = w4; ldW = 16;  p = g & 1; kt = g >> 1; is16 = true; }
  u16x8 o;
  #pragma unroll
  for (int j = 0; j < 8; j++) {
    int k, col;
    if (is16) { col = l & 15;             k = kt*32 + ((l >> 4) & 3)*8 + j; }
    else      { col = Mt*32 + (l & 31);   k = kt*16 + (l >> 5)*8 + j; }
    float x = W[k * ldW + col];
    _Float16 h = (_Float16)x;                       // RNE
    _Float16 lo = (_Float16)((x - (float)h) * 2048.0f);
    o[j] = __builtin_bit_cast(unsigned short, (p == 0) ? h : lo);
  }
  ((u16x8*)F)[f * 64 + l] = o;
}

// ---------------------------------------------------------------------------
// Main fused kernel. LDS map (66 KiB):
//   H0 = [0,32768)      : buf0, planes hi / scaled-lo at +0/+16384,
//                         row-major [64][128] f16, row stride 256B,
//                         byte col XOR-swizzled with ((row&15)<<4)
//   H1 = [32768,65536)  : buf1 same layout
//   edge staging [0,3584)       aliases H0 (dead before L1 writes H0)
//   pose [32768,36864)          aliases H1 (dead before L2 writes H1)
//   BIAS [65536,67136)  : b1|b2|b3 (128 f32 each) + b4 (16 f32)
// Per tile: edges->pose (fp32 exact) -> L1 -> H0 -> L2 -> H1 -> L3 -> H0
//   -> L4 -> out.  Each matmul: 3 f16 MFMAs per k-tile (Wh*xh -> acc0;
//   Wl*xh, Wh*xl -> accL), epilogue y = acc0 + accL*2^-11.
// Bank balance (by construction): ds_read_b128 = 8 dwords/bank exactly
// (1 KiB/wave floor); ds_write_b64 = 4 dwords/bank exactly.
// ---------------------------------------------------------------------------
__global__ __launch_bounds__(256, 2) void mlp_main(
    const float* __restrict__ edges, const unsigned short* __restrict__ Fw,
    const float* b1, const float* b2, const float* b3, const float* b4,
    float* out) {
  __shared__ __align__(16) char smem[65536 + 2048];
  const int tid = threadIdx.x;
  const int l   = tid & 63;
  const int w   = tid >> 6;      // wave 0..3 : owns hidden rows [32w, 32w+32)
  const int l31 = l & 31;
  const int lh  = l >> 5;        // k-half for 32x32x16 fragments

  // ---- load weight fragments into registers (persistent) ----
  const f16x8* F = (const f16x8*)Fw;
  f16x8 w1f[2], w2f[8][2], w3f[8][2], w4f[4][2];
  #pragma unroll
  for (int p = 0; p < 2; p++) w1f[p] = F[(w*2 + p)*64 + l];
  #pragma unroll
  for (int kt = 0; kt < 8; kt++) {
    w2f[kt][0] = F[(8  + (w*8 + kt)*2    )*64 + l];
    w2f[kt][1] = F[(8  + (w*8 + kt)*2 + 1)*64 + l];
    w3f[kt][0] = F[(72 + (w*8 + kt)*2    )*64 + l];
    w3f[kt][1] = F[(72 + (w*8 + kt)*2 + 1)*64 + l];
  }
  #pragma unroll
  for (int kt = 0; kt < 4; kt++) {
    w4f[kt][0] = F[(136 + kt*2    )*64 + l];
    w4f[kt][1] = F[(136 + kt*2 + 1)*64 + l];
  }

  const int H0 = 0, H1 = 32768, PL = 16384;
  const int POSE = 32768, POSE_PL = 2048;
  const int BIAS = 65536, BIAS4 = 65536 + 1536;
  const int sw = (l & 15) << 4;  // XOR swizzle for rows e with (e&15)==(l&15)

  // ---- stage biases to LDS once (first in-loop __syncthreads covers use) ----
  if (tid < 96) {
    const float* bsrc = (tid < 32) ? b1 : (tid < 64) ? b2 : b3;
    int idx = tid & 31;
    float4 v = ((const float4*)bsrc)[idx];
    *(float4*)(smem + BIAS + (tid >> 5)*512 + idx*16) = v;
  } else if (tid < 100) {
    float4 v = ((const float4*)b4)[tid - 96];
    *(float4*)(smem + BIAS4 + (tid - 96)*16) = v;
  }

  // acc0 init = bias (C-operand): lane covers hidden rows w*32+lh*4+q*8+i
  auto bias_acc = [&](int bi) -> f32x16 {
    const char* bb = smem + BIAS + bi*512 + w*128 + lh*16;
    f32x16 a;
    #pragma unroll
    for (int q = 0; q < 4; q++) {
      f32x4 t = *(const f32x4*)(bb + q*32);
      #pragma unroll
      for (int i = 0; i < 4; i++) a[q*4 + i] = t[i];
    }
    return a;
  };

  // epilogue: combine planes -> relu -> f16 split -> LDS b64 stores
  auto write_act = [&](int outb, int nt, const f32x16& a0, const f32x16& aL) {
    int e = nt*32 + l31;
    int rowb = outb + e*256;
    int cb0 = w*64 + lh*8;         // byte col base = (w*32+lh*4)*2
    #pragma unroll
    for (int q = 0; q < 4; q++) {
      float v0 = fmaxf(fmaf(aL[q*4+0], INV2K, a0[q*4+0]), 0.f);
      float v1 = fmaxf(fmaf(aL[q*4+1], INV2K, a0[q*4+1]), 0.f);
      float v2 = fmaxf(fmaf(aL[q*4+2], INV2K, a0[q*4+2]), 0.f);
      float v3 = fmaxf(fmaf(aL[q*4+3], INV2K, a0[q*4+3]), 0.f);
      unsigned int h0, lo0, h1, lo1;
      split_pair_f16(v0, v1, h0, lo0);
      split_pair_f16(v2, v3, h1, lo1);
      int cb = (cb0 + q*16) ^ sw;
      *(u32x2*)(smem + rowb +      cb) = (u32x2){h0, h1};
      *(u32x2*)(smem + rowb + PL + cb) = (u32x2){lo0, lo1};
    }
  };

  // one 128->128 layer; edge-tiles sequential (acc pressure 32 VGPR);
  // per k-tile 3 MFMAs on 2 independent accumulator chains, distance >= 2
  auto layer = [&](int inb, int outb, f16x8 (&wf)[8][2], int bi) {
    #pragma unroll
    for (int nt = 0; nt < 2; nt++) {
      f32x16 a0 = bias_acc(bi);
      f32x16 aL = (f32x16)0.0f;
      #pragma unroll
      for (int kt = 0; kt < 8; kt++) {
        int kb = kt*32 + lh*16;
        int ad = inb + (nt*32 + l31)*256 + (kb ^ sw);
        f16x8 bh = *(const f16x8*)(smem + ad);
        f16x8 bl = *(const f16x8*)(smem + ad + PL);
        aL = mfma32(wf[kt][1], bh, aL);
        a0 = mfma32(wf[kt][0], bh, a0);
        aL = mfma32(wf[kt][0], bl, aL);
      }
      write_act(outb, nt, a0, aL);
    }
    __syncthreads();
  };

  for (int tile = blockIdx.x; tile < NTILES; tile += (int)gridDim.x) {
    // ---- stage 64 edges (896 floats) coalesced into LDS ----
    if (tid < 224) {
      float4 v = ((const float4*)edges)[tile*224 + tid];
      *(float4*)(smem + tid*16) = v;
    }
    __syncthreads();

    // ---- geometry (fp32, exact): rel_pose -> f16 hi / scaled-lo planes ----
    if (tid < 64) {
      const float* ep = (const float*)smem + tid*14;
      float aw = ep[0], ax = ep[1], ay = ep[2], az = ep[3];
      float t1x = ep[4], t1y = ep[5], t1z = ep[6];
      float bw = ep[7], bx = ep[8], by = ep[9], bz = ep[10];
      float t2x = ep[11], t2y = ep[12], t2z = ep[13];
      float r1[9], r2[9], R[9];
      q2m(aw, ax, ay, az, r1);
      q2m(bw, bx, by, bz, r2);
      #pragma unroll
      for (int i = 0; i < 3; i++)
        #pragma unroll
        for (int k2 = 0; k2 < 3; k2++)
          R[i*3 + k2] = r1[i*3+0]*r2[k2*3+0] + r1[i*3+1]*r2[k2*3+1] + r1[i*3+2]*r2[k2*3+2];
      float tx = t1x - (R[0]*t2x + R[1]*t2y + R[2]*t2z);
      float ty = t1y - (R[3]*t2x + R[4]*t2y + R[5]*t2z);
      float tz = t1z - (R[6]*t2x + R[7]*t2y + R[8]*t2z);
      float pose[16] = {R[0], R[1], R[2], tx,
                        R[3], R[4], R[5], ty,
                        R[6], R[7], R[8], tz,
                        0.f,  0.f,  0.f,  1.f};
      unsigned int hd[8], ld[8];
      #pragma unroll
      for (int i = 0; i < 8; i++)
        split_pair_f16(pose[2*i], pose[2*i+1], hd[i], ld[i]);
      char* pb = smem + POSE + tid*32;      // row stride 32B, no swizzle
      *(u32x4*)(pb)                 = (u32x4){hd[0], hd[1], hd[2], hd[3]};
      *(u32x4*)(pb + 16)            = (u32x4){hd[4], hd[5], hd[6], hd[7]};
      *(u32x4*)(pb + POSE_PL)       = (u32x4){ld[0], ld[1], ld[2], ld[3]};
      *(u32x4*)(pb + POSE_PL + 16)  = (u32x4){ld[4], ld[5], ld[6], ld[7]};
    }
    __syncthreads();

    // ---- L1: pose(16) -> H0(128), K=16 with 32x32x16, bias in C ----
    {
      #pragma unroll
      for (int nt = 0; nt < 2; nt++) {
        f32x16 a0 = bias_acc(0);
        f32x16 aL = (f32x16)0.0f;
        int pr = POSE + (nt*32 + l31)*32 + lh*16;
        f16x8 bh = *(const f16x8*)(smem + pr);
        f16x8 bl = *(const f16x8*)(smem + pr + POSE_PL);
        aL = mfma32(w1f[1], bh, aL);
        a0 = mfma32(w1f[0], bh, a0);
        aL = mfma32(w1f[0], bl, aL);
        write_act(H0, nt, a0, aL);
      }
      __syncthreads();
    }

    // ---- L2: H0 -> H1 ; L3: H1 -> H0 ----
    layer(H0, H1, w2f, 1);
    layer(H1, H0, w3f, 2);

    // ---- L4: H0(128) -> out(16) with 16x16x32; wave w owns edges [16w,16w+16) ----
    {
      int kg = (l >> 4) & 3;
      f32x4 a4 = *(const f32x4*)(smem + BIAS4 + kg*16);   // bias in C
      f32x4 aL = (f32x4)0.0f;
      int e = w*16 + (l & 15);
      int rowb = H0 + e*256;
      #pragma unroll
      for (int kt = 0; kt < 4; kt++) {
        int kb = kt*64 + kg*16;
        f16x8 bh = *(const f16x8*)(smem + rowb +      (kb ^ sw));
        f16x8 bl = *(const f16x8*)(smem + rowb + PL + (kb ^ sw));
        aL = mfma16(w4f[kt][1], bh, aL);
        a4 = mfma16(w4f[kt][0], bh, a4);
        aL = mfma16(w4f[kt][0], bl, aL);
      }
      float4 o;
      o.x = fmaf(aL[0], INV2K, a4[0]);
      o.y = fmaf(aL[1], INV2K, a4[1]);
      o.z = fmaf(aL[2], INV2K, a4[2]);
      o.w = fmaf(aL[3], INV2K, a4[3]);
      *(float4*)(out + (tile*64 + e)*16 + kg*4) = o;
    }
    __syncthreads();  // protect H0 before next tile's staging writes
  }
}

extern "C" void kernel_launch(void* const* d_in, const int* in_sizes, int n_in,
                              void* d_out, int out_size, void* d_ws, size_t ws_size,
                              hipStream_t stream) {
  (void)in_sizes; (void)n_in; (void)out_size; (void)ws_size;
  const float* edges = (const float*)d_in[0];
  const float* w1 = (const float*)d_in[1];
  const float* b1 = (const float*)d_in[2];
  const float* w2 = (const float*)d_in[3];
  const float* b2 = (const float*)d_in[4];
  const float* w3 = (const float*)d_in[5];
  const float* b3 = (const float*)d_in[6];
  const float* w4 = (const float*)d_in[7];
  const float* b4 = (const float*)d_in[8];
  unsigned short* F = (unsigned short*)d_ws;   // needs 144*64*16 = 147456 B
  float* out = (float*)d_out;

  prep_frags<<<36, 256, 0, stream>>>(w1, w2, w3, w4, F);
  mlp_main<<<GRID_MAIN, 256, 0, stream>>>(edges, F, b1, b2, b3, b4, out);
}